// Round 18
// baseline (196.097 us; speedup 1.0000x reference)
//
#include <hip/hip_runtime.h>
#include <hip/hip_bf16.h>

#define N_ 16
#define D_ 2048
#define H_ 32
#define W_ 32
#define HW_ 1024
#define F_ 512

typedef unsigned short u16;
typedef unsigned int u32;
typedef __attribute__((ext_vector_type(8))) short bf16x8;
typedef __attribute__((ext_vector_type(4))) float f32x4;

__device__ __forceinline__ u16 f2bf(float f) {
  __hip_bfloat16 h = __float2bfloat16(f);
  union { __hip_bfloat16 h; u16 u; } c; c.h = h;
  return c.u;
}
__device__ __forceinline__ u32 f2bf2(float lo, float hi) {
  return (u32)f2bf(lo) | ((u32)f2bf(hi) << 16);
}

// ---- K0: zero sumsq+gbuf (192 KB contiguous) ----
__global__ __launch_bounds__(256) void k_zero(float* __restrict__ p) {
  int i = blockIdx.x * 256 + threadIdx.x;
  ((float4*)p)[i] = (float4){0.f, 0.f, 0.f, 0.f};
}

// ---- K1: sum of squares over channel dim -> sumsq[n][hw] (atomic partials) ----
__global__ __launch_bounds__(256) void k_sumsq(const float* __restrict__ x, float* __restrict__ sumsq) {
  const int n = blockIdx.x;        // 16
  const int dc = blockIdx.y;       // 32 chunks x 64 d
  const int t = threadIdx.x;
  const float* xp = x + ((size_t)n * D_ + (size_t)dc * 64) * HW_;
  float s0 = 0.f, s1 = 0.f, s2 = 0.f, s3 = 0.f;
  for (int d = 0; d < 64; ++d) {
    const float* row = xp + (size_t)d * HW_;
    float v0 = row[t], v1 = row[t + 256], v2 = row[t + 512], v3 = row[t + 768];
    s0 += v0 * v0; s1 += v1 * v1; s2 += v2 * v2; s3 += v3 * v3;
  }
  atomicAdd(&sumsq[n * HW_ + t      ], s0);
  atomicAdd(&sumsq[n * HW_ + t + 256], s1);
  atomicAdd(&sumsq[n * HW_ + t + 512], s2);
  atomicAdd(&sumsq[n * HW_ + t + 768], s3);
}

// ---- K3: proj_w fp32 -> bf16, fragment-packed: packB[wq][kt][nf][lane][8] ----
__global__ __launch_bounds__(256) void k_wconv(const float* __restrict__ w, u16* __restrict__ packB) {
  const int i = blockIdx.x * 256 + threadIdx.x;   // 0..131071
  const int lane = i & 63, nf = (i >> 6) & 3, kt = (i >> 8) & 63, wq = i >> 14;  // wq 0..7
  const int r15 = lane & 15, hi = lane >> 4;
  const int f = wq * 64 + nf * 16 + r15;
  const int k = kt * 32 + hi * 8;
  const float* src = w + (size_t)f * D_ + k;
  float4 v0 = *(const float4*)(src);
  float4 v1 = *(const float4*)(src + 4);
  u16 r[8] = { f2bf(v0.x), f2bf(v0.y), f2bf(v0.z), f2bf(v0.w),
               f2bf(v1.x), f2bf(v1.y), f2bf(v1.z), f2bf(v1.w) };
  *(uint4*)(packB + (size_t)i * 8) = *(const uint4*)r;
}

// ---- K4: FUSED box + GEMM, register-box + double-buffered Af, 1 barrier/step ----
// 256 blocks, 512 thr. Block owns 64 hw rows (h rows hA, hA+1), full F=512.
// Box threads t<256: (dp 0..15, w4 0..7, rh 0..1) -> d-pair x w-quad x 1 row.
// Step kt: [load B(kt+1), x(kt+2)] ; box(kt+1)->Af[(kt+1)&1] (regs only, u32
// LDS writes) overlapping MFMA(kt)<-Af[kt&1] ; barrier.
__global__ __launch_bounds__(512) void k_boxgemm(const float* __restrict__ x,
    const float* __restrict__ sumsq, const float* __restrict__ pvec,
    const u16* __restrict__ packB, const float* __restrict__ bias,
    float* __restrict__ gbuf, float* __restrict__ outL) {
  const int mt = blockIdx.x;            // 0..255
  const int n  = mt >> 4;
  const int hseg = mt & 15;
  const int hA = hseg * 2;
  const int hw0 = hseg * 64;
  const int t = threadIdx.x;
  const int lane = t & 63, wv = t >> 6;
  const int r15 = lane & 15, hi = lane >> 4;
  const float p = pvec[0];
  const bool p3c = (p == 3.0f);

  // box-thread mapping (t < 256)
  const bool bxt = (t < 256);
  const int dp = t >> 4;                // 0..15 (d-pair)
  const int w4 = (t >> 1) & 7;          // 0..7
  const int rh = t & 1;                 // 0..1
  const int wq = w4 * 4;
  const int h_out = hA + rh;

  __shared__ __align__(16) float smem[128 * 68];   // Af 2x4KB | rnl ; epilogue ct
  u16* Af = (u16*)smem;                  // [2][2048] u16
  float* rnl = smem + 2048;              // [4][32] f32 (rows hA-1..hA+2)
  __shared__ float s_sq[8][64];
  __shared__ float s_rn[64];

  if (t < 128) {
    int jj = t >> 5, w = t & 31;
    int hp = hA - 1 + jj;
    float r = 0.f;
    if (hp >= 0 && hp < H_) r = 1.0f / fmaxf(sqrtf(sumsq[n * HW_ + hp * W_ + w]), 1e-12f);
    rnl[jj * 32 + w] = r;
  }

  f32x4 acc[4][4];
  #pragma unroll
  for (int a = 0; a < 4; ++a)
    #pragma unroll
    for (int b = 0; b < 4; ++b) acc[a][b] = (f32x4){0.f, 0.f, 0.f, 0.f};

  const float4 zero4 = {0.f, 0.f, 0.f, 0.f};
  const int hr0 = h_out - 1, hr2 = h_out + 1;
  const bool v0ok = (hr0 >= 0), v2ok = (hr2 < H_);
  const float* xp0 = x + ((size_t)(n * D_ + 2 * dp)) * HW_ + (v0ok ? hr0 : 0) * W_ + wq;
  const float* xp1 = x + ((size_t)(n * D_ + 2 * dp)) * HW_ + h_out * W_ + wq;
  const float* xp2 = x + ((size_t)(n * D_ + 2 * dp)) * HW_ + (v2ok ? hr2 : 0) * W_ + wq;

  float4 xa[6], xn[6];
  auto loadx = [&](int kt, float4* X) {
    size_t o = (size_t)kt * 32 * HW_;
    X[0] = v0ok ? *(const float4*)(xp0 + o) : zero4;
    X[1] = v0ok ? *(const float4*)(xp0 + o + HW_) : zero4;
    X[2] = *(const float4*)(xp1 + o);
    X[3] = *(const float4*)(xp1 + o + HW_);
    X[4] = v2ok ? *(const float4*)(xp2 + o) : zero4;
    X[5] = v2ok ? *(const float4*)(xp2 + o + HW_) : zero4;
  };
  auto boxc = [&](int kt, float4* X) {
    float4 rn0 = *(const float4*)(rnl + rh * 32 + wq);
    float4 rn1 = *(const float4*)(rnl + (rh + 1) * 32 + wq);
    float4 rn2 = *(const float4*)(rnl + (rh + 2) * 32 + wq);
    float4 ve[2][3];
    #pragma unroll
    for (int e = 0; e < 2; ++e) {
      ve[e][0].x = X[e].x * rn0.x;     ve[e][0].y = X[e].y * rn0.y;
      ve[e][0].z = X[e].z * rn0.z;     ve[e][0].w = X[e].w * rn0.w;
      ve[e][1].x = X[2 + e].x * rn1.x; ve[e][1].y = X[2 + e].y * rn1.y;
      ve[e][1].z = X[2 + e].z * rn1.z; ve[e][1].w = X[2 + e].w * rn1.w;
      ve[e][2].x = X[4 + e].x * rn2.x; ve[e][2].y = X[4 + e].y * rn2.y;
      ve[e][2].z = X[4 + e].z * rn2.z; ve[e][2].w = X[4 + e].w * rn2.w;
    }
    // GeM partial from center row (h_out)
    float g[2];
    #pragma unroll
    for (int e = 0; e < 2; ++e) {
      float cx = fmaxf(ve[e][1].x, 1e-6f), cy = fmaxf(ve[e][1].y, 1e-6f);
      float cz = fmaxf(ve[e][1].z, 1e-6f), cw = fmaxf(ve[e][1].w, 1e-6f);
      if (p3c) g[e] = cx * cx * cx + cy * cy * cy + cz * cz * cz + cw * cw * cw;
      else     g[e] = __powf(cx, p) + __powf(cy, p) + __powf(cz, p) + __powf(cw, p);
    }
    // reduce over (rh, w4) within 16-lane group; one atomic per d
    #pragma unroll
    for (int e = 0; e < 2; ++e) {
      g[e] += __shfl_xor(g[e], 1, 16);
      g[e] += __shfl_xor(g[e], 2, 16);
      g[e] += __shfl_xor(g[e], 4, 16);
      g[e] += __shfl_xor(g[e], 8, 16);
    }
    if ((lane & 15) == 0) {
      atomicAdd(&gbuf[n * D_ + kt * 32 + 2 * dp    ], g[0]);
      atomicAdd(&gbuf[n * D_ + kt * 32 + 2 * dp + 1], g[1]);
    }
    // horizontal 3-tap (shfl within 16-lane group, stride 2 = w4 +/- 1)
    float4 o[2];
    #pragma unroll
    for (int e = 0; e < 2; ++e) {
      float4 h[3];
      #pragma unroll
      for (int k = 0; k < 3; ++k) {
        float lf = __shfl_up(ve[e][k].w, 2, 16);
        float rf = __shfl_down(ve[e][k].x, 2, 16);
        if (w4 == 0) lf = 0.f;
        if (w4 == 7) rf = 0.f;
        h[k].x = lf + ve[e][k].x + ve[e][k].y;
        h[k].y = ve[e][k].x + ve[e][k].y + ve[e][k].z;
        h[k].z = ve[e][k].y + ve[e][k].z + ve[e][k].w;
        h[k].w = ve[e][k].z + ve[e][k].w + rf;
      }
      o[e].x = h[0].x + h[1].x + h[2].x;
      o[e].y = h[0].y + h[1].y + h[2].y;
      o[e].z = h[0].z + h[1].z + h[2].z;
      o[e].w = h[0].w + h[1].w + h[2].w;
    }
    // packed u32 writes into Af[kt&1] (lo = even d, hi = odd d)
    u32* d32 = (u32*)(Af + (kt & 1) * 2048);
    const float oe[4] = {o[0].x, o[0].y, o[0].z, o[0].w};
    const float oo[4] = {o[1].x, o[1].y, o[1].z, o[1].w};
    #pragma unroll
    for (int i = 0; i < 4; ++i) {
      int r = rh * 32 + wq + i;
      d32[(r >> 4) * 256 + (dp >> 2) * 64 + (r & 15) * 4 + (dp & 3)] = f2bf2(oe[i], oo[i]);
    }
  };

  // B fragments
  const u16* bbase = packB + (size_t)wv * 131072 + lane * 8;
  bf16x8 bc[4], bn[4];
  #pragma unroll
  for (int nf = 0; nf < 4; ++nf) bc[nf] = *(const bf16x8*)(bbase + nf * 512);

  // prologue: rnl must be visible before box(0)
  __syncthreads();
  if (bxt) {
    loadx(0, xa);
    boxc(0, xa);          // writes Af[0], GeM(0)
    loadx(1, xa);         // xa <- x(1)
  }
  __syncthreads();        // Af[0] visible

  for (int kt = 0; kt < 64; ++kt) {
    if (kt + 1 < 64) {
      #pragma unroll
      for (int nf = 0; nf < 4; ++nf)
        bn[nf] = *(const bf16x8*)(bbase + ((size_t)(kt + 1) * 4 + nf) * 512);
    }
    if (bxt && kt + 2 < 64) loadx(kt + 2, xn);
    if (bxt && kt + 1 < 64) boxc(kt + 1, xa);   // writes Af[(kt+1)&1]

    const u16* Ar = Af + (kt & 1) * 2048;
    bf16x8 af[4];
    #pragma unroll
    for (int mf = 0; mf < 4; ++mf)
      af[mf] = *(const bf16x8*)(Ar + mf * 512 + lane * 8);
    #pragma unroll
    for (int mf = 0; mf < 4; ++mf)
      #pragma unroll
      for (int nf = 0; nf < 4; ++nf)
        acc[mf][nf] = __builtin_amdgcn_mfma_f32_16x16x32_bf16(af[mf], bc[nf], acc[mf][nf], 0, 0, 0);

    if (bxt) {
      #pragma unroll
      for (int q = 0; q < 6; ++q) xa[q] = xn[q];
    }
    #pragma unroll
    for (int nf = 0; nf < 4; ++nf) bc[nf] = bn[nf];
    __syncthreads();      // Af[(kt+1)&1] ready; reads of Af[kt&1] done
  }

  // ---- epilogue: bias, per-row (hw) l2 norm over all 512 f, transposed store ----
  float badd[4];
  #pragma unroll
  for (int nf = 0; nf < 4; ++nf) badd[nf] = bias[wv * 64 + nf * 16 + r15];
  #pragma unroll
  for (int mf = 0; mf < 4; ++mf)
    #pragma unroll
    for (int nf = 0; nf < 4; ++nf)
      #pragma unroll
      for (int j = 0; j < 4; ++j) acc[mf][nf][j] += badd[nf];

  #pragma unroll
  for (int mf = 0; mf < 4; ++mf)
    #pragma unroll
    for (int j = 0; j < 4; ++j) {
      float s = 0.f;
      #pragma unroll
      for (int nf = 0; nf < 4; ++nf) { float v = acc[mf][nf][j]; s += v * v; }
      s += __shfl_xor(s, 1); s += __shfl_xor(s, 2); s += __shfl_xor(s, 4); s += __shfl_xor(s, 8);
      if ((lane & 15) == 0) s_sq[wv][mf * 16 + hi * 4 + j] = s;
    }
  __syncthreads();
  if (t < 64) {
    float s = 0.f;
    #pragma unroll
    for (int w8 = 0; w8 < 8; ++w8) s += s_sq[w8][t];
    s_rn[t] = 1.0f / fmaxf(sqrtf(s), 1e-12f);
  }
  __syncthreads();

  float* ct = smem;   // [128 f-rows][68] fp32
  for (int nf = 0; nf < 4; ++nf) {
    const int fi = wv * 16 + r15;
    #pragma unroll
    for (int mf = 0; mf < 4; ++mf)
      #pragma unroll
      for (int j = 0; j < 4; ++j) {
        int m = mf * 16 + hi * 4 + j;
        ct[fi * 68 + m] = acc[mf][nf][j] * s_rn[m];
      }
    __syncthreads();
    {
      int fr = t >> 2, mq = t & 3;
      int f = (fr >> 4) * 64 + nf * 16 + (fr & 15);
      float* dst = outL + ((size_t)(n * F_ + f)) * HW_ + hw0 + mq * 16;
      const float* srcp = ct + fr * 68 + mq * 16;
      float4 a0 = *(const float4*)(srcp);
      float4 a1 = *(const float4*)(srcp + 4);
      float4 a2 = *(const float4*)(srcp + 8);
      float4 a3 = *(const float4*)(srcp + 12);
      *(float4*)(dst) = a0; *(float4*)(dst + 4) = a1;
      *(float4*)(dst + 8) = a2; *(float4*)(dst + 12) = a3;
    }
    __syncthreads();
  }
}

// ---- K5: GeM finalize: gg = (gbuf/1024)^(1/p) ----
__global__ __launch_bounds__(256) void k_gem_fin(const float* __restrict__ gbuf,
    const float* __restrict__ pvec, float* __restrict__ gg) {
  int i = blockIdx.x * 256 + threadIdx.x;
  float p = pvec[0];
  float m = gbuf[i] * (1.0f / 1024.0f);
  gg[i] = (p == 3.0f) ? cbrtf(m) : powf(m, 1.0f / p);
}

// ---- K6: gproj[n][f] = dot(gg[n], W[f]) + b[f] ----
__global__ __launch_bounds__(256) void k_gproj(const float* __restrict__ w,
    const float* __restrict__ bias, const float* __restrict__ gg,
    float* __restrict__ gproj) {
  const int f = blockIdx.x;
  const int t = threadIdx.x;
  float wreg[8];
  #pragma unroll
  for (int j = 0; j < 8; ++j) wreg[j] = w[(size_t)f * D_ + t + j * 256];
  __shared__ float red[4];
  const int lane = t & 63, wv = t >> 6;
  for (int n = 0; n < N_; ++n) {
    float s = 0.f;
    #pragma unroll
    for (int j = 0; j < 8; ++j) s += wreg[j] * gg[n * D_ + t + j * 256];
    #pragma unroll
    for (int off = 32; off >= 1; off >>= 1) s += __shfl_down(s, off);
    if (lane == 0) red[wv] = s;
    __syncthreads();
    if (t == 0) gproj[n * F_ + f] = red[0] + red[1] + red[2] + red[3] + bias[f];
    __syncthreads();
  }
}

// ---- K7: l2norm g rows -> d_out[0:8192] ----
__global__ __launch_bounds__(512) void k_gnorm(const float* __restrict__ gproj, float* __restrict__ outg) {
  const int n = blockIdx.x;
  const int t = threadIdx.x;
  float v = gproj[n * F_ + t];
  float s = v * v;
  const int lane = t & 63, wv = t >> 6;
  #pragma unroll
  for (int off = 32; off >= 1; off >>= 1) s += __shfl_down(s, off);
  __shared__ float red[8];
  __shared__ float rtot;
  if (lane == 0) red[wv] = s;
  __syncthreads();
  if (t == 0) {
    float a = 0.f;
    #pragma unroll
    for (int i = 0; i < 8; ++i) a += red[i];
    rtot = 1.0f / fmaxf(sqrtf(a), 1e-12f);
  }
  __syncthreads();
  outg[n * F_ + t] = v * rtot;
}

extern "C" void kernel_launch(void* const* d_in, const int* in_sizes, int n_in,
                              void* d_out, int out_size, void* d_ws, size_t ws_size,
                              hipStream_t stream) {
  const float* x  = (const float*)d_in[0];
  const float* pw = (const float*)d_in[1];
  const float* pb = (const float*)d_in[2];
  const float* pv = (const float*)d_in[3];
  float* out = (float*)d_out;

  char* ws = (char*)d_ws;
  float* sumsq = (float*)ws;                                   // 64 KB
  float* gbuf  = (float*)(ws + 65536);                         // 128 KB
  float* gg    = (float*)(ws + 65536 + 131072);                // 128 KB
  float* gproj = (float*)(ws + 65536 + 2 * 131072);            // 32 KB
  u16*   packB = (u16*)(ws + 65536 + 2 * 131072 + 32768);      // 2 MiB

  k_zero<<<dim3(48), dim3(256), 0, stream>>>(sumsq);           // sumsq + gbuf
  k_sumsq<<<dim3(16, 32), dim3(256), 0, stream>>>(x, sumsq);
  k_wconv<<<dim3(512), dim3(256), 0, stream>>>(pw, packB);
  k_boxgemm<<<dim3(256), dim3(512), 0, stream>>>(x, sumsq, pv, packB, pb, gbuf, out + N_ * F_);
  k_gem_fin<<<dim3(128), dim3(256), 0, stream>>>(gbuf, pv, gg);
  k_gproj<<<dim3(512), dim3(256), 0, stream>>>(pw, pb, gg, gproj);
  k_gnorm<<<dim3(16), dim3(512), 0, stream>>>(gproj, out);
}

// Round 19
// 141.930 us; speedup vs baseline: 1.3816x; 1.3816x over previous
//
#include <hip/hip_runtime.h>
#include <hip/hip_bf16.h>

#define N_ 16
#define D_ 2048
#define H_ 32
#define W_ 32
#define HW_ 1024
#define F_ 512

typedef unsigned short u16;
typedef unsigned int u32;
typedef __attribute__((ext_vector_type(8))) short bf16x8;
typedef __attribute__((ext_vector_type(4))) float f32x4;

__device__ __forceinline__ u16 f2bf(float f) {
  __hip_bfloat16 h = __float2bfloat16(f);
  union { __hip_bfloat16 h; u16 u; } c; c.h = h;
  return c.u;
}
__device__ __forceinline__ u32 f2bf2(float lo, float hi) {
  return (u32)f2bf(lo) | ((u32)f2bf(hi) << 16);
}

#define GLD_LDS16(gp, lp) __builtin_amdgcn_global_load_lds( \
    (const __attribute__((address_space(1))) void*)(gp), \
    (__attribute__((address_space(3))) void*)(lp), 16, 0, 0)

// ---- K0: zero sumsq+gbuf (192 KB contiguous) ----
__global__ __launch_bounds__(256) void k_zero(float* __restrict__ p) {
  int i = blockIdx.x * 256 + threadIdx.x;
  ((float4*)p)[i] = (float4){0.f, 0.f, 0.f, 0.f};
}

// ---- K1: sum of squares over channel dim -> sumsq[n][hw] (atomic partials) ----
__global__ __launch_bounds__(256) void k_sumsq(const float* __restrict__ x, float* __restrict__ sumsq) {
  const int n = blockIdx.x;        // 16
  const int dc = blockIdx.y;       // 32 chunks x 64 d
  const int t = threadIdx.x;
  const float* xp = x + ((size_t)n * D_ + (size_t)dc * 64) * HW_;
  float s0 = 0.f, s1 = 0.f, s2 = 0.f, s3 = 0.f;
  for (int d = 0; d < 64; ++d) {
    const float* row = xp + (size_t)d * HW_;
    float v0 = row[t], v1 = row[t + 256], v2 = row[t + 512], v3 = row[t + 768];
    s0 += v0 * v0; s1 += v1 * v1; s2 += v2 * v2; s3 += v3 * v3;
  }
  atomicAdd(&sumsq[n * HW_ + t      ], s0);
  atomicAdd(&sumsq[n * HW_ + t + 256], s1);
  atomicAdd(&sumsq[n * HW_ + t + 512], s2);
  atomicAdd(&sumsq[n * HW_ + t + 768], s3);
}

// ---- K2: fused-dj float4 box + GeM partials (r16 form) ----
__global__ __launch_bounds__(256) void k_box2(const float* __restrict__ x,
    const float* __restrict__ sumsq, const float* __restrict__ pvec,
    float* __restrict__ gbuf, u16* __restrict__ packA) {
  const int n = blockIdx.x, ht = blockIdx.y, dc = blockIdx.z;
  const int h0 = ht * 4, d0 = dc * 64;
  const int t = threadIdx.x;
  const int w4 = t & 7, dg = t >> 3;
  const int wq = w4 * 4;
  const float p = pvec[0];
  const bool p3 = (p == 3.0f);

  __shared__ __align__(16) u32 sbox[128 * 34];   // [hw 128][d-pair 32 pad->34]
  __shared__ __align__(16) float rnl[6][32];

  if (t < 192) {
    int jj = t >> 5, w = t & 31;
    int hp = h0 - 1 + jj;
    float r = 0.f;
    if (hp >= 0 && hp < H_) r = 1.0f / fmaxf(sqrtf(sumsq[n * HW_ + hp * W_ + w]), 1e-12f);
    rnl[jj][w] = r;
  }
  __syncthreads();

  const float* base0 = x + ((size_t)(n * D_ + d0 + dg * 2)) * HW_ + wq;
  const float* base1 = base0 + HW_;

  float4 v0[6], v1[6];
  #pragma unroll
  for (int jj = 0; jj < 6; ++jj) {
    int hp = h0 - 1 + jj;
    if (hp >= 0 && hp < H_) {
      float4 a = *(const float4*)(base0 + hp * W_);
      float4 b = *(const float4*)(base1 + hp * W_);
      float4 rr = *(const float4*)(&rnl[jj][wq]);
      v0[jj].x = a.x * rr.x; v0[jj].y = a.y * rr.y; v0[jj].z = a.z * rr.z; v0[jj].w = a.w * rr.w;
      v1[jj].x = b.x * rr.x; v1[jj].y = b.y * rr.y; v1[jj].z = b.z * rr.z; v1[jj].w = b.w * rr.w;
    } else {
      v0[jj] = (float4){0.f, 0.f, 0.f, 0.f};
      v1[jj] = (float4){0.f, 0.f, 0.f, 0.f};
    }
  }

  float g0 = 0.f, g1 = 0.f;
  #pragma unroll
  for (int jj = 1; jj <= 4; ++jj) {
    float c0x = fmaxf(v0[jj].x, 1e-6f), c0y = fmaxf(v0[jj].y, 1e-6f);
    float c0z = fmaxf(v0[jj].z, 1e-6f), c0w = fmaxf(v0[jj].w, 1e-6f);
    float c1x = fmaxf(v1[jj].x, 1e-6f), c1y = fmaxf(v1[jj].y, 1e-6f);
    float c1z = fmaxf(v1[jj].z, 1e-6f), c1w = fmaxf(v1[jj].w, 1e-6f);
    if (p3) {
      g0 += c0x * c0x * c0x + c0y * c0y * c0y + c0z * c0z * c0z + c0w * c0w * c0w;
      g1 += c1x * c1x * c1x + c1y * c1y * c1y + c1z * c1z * c1z + c1w * c1w * c1w;
    } else {
      g0 += __powf(c0x, p) + __powf(c0y, p) + __powf(c0z, p) + __powf(c0w, p);
      g1 += __powf(c1x, p) + __powf(c1y, p) + __powf(c1z, p) + __powf(c1w, p);
    }
  }

  #pragma unroll
  for (int jj = 0; jj < 6; ++jj) {
    float lf0 = __shfl_up(v0[jj].w, 1, 8), rf0 = __shfl_down(v0[jj].x, 1, 8);
    float lf1 = __shfl_up(v1[jj].w, 1, 8), rf1 = __shfl_down(v1[jj].x, 1, 8);
    if (w4 == 0) { lf0 = 0.f; lf1 = 0.f; }
    if (w4 == 7) { rf0 = 0.f; rf1 = 0.f; }
    float4 h0v, h1v;
    h0v.x = lf0 + v0[jj].x + v0[jj].y;
    h0v.y = v0[jj].x + v0[jj].y + v0[jj].z;
    h0v.z = v0[jj].y + v0[jj].z + v0[jj].w;
    h0v.w = v0[jj].z + v0[jj].w + rf0;
    h1v.x = lf1 + v1[jj].x + v1[jj].y;
    h1v.y = v1[jj].x + v1[jj].y + v1[jj].z;
    h1v.z = v1[jj].y + v1[jj].z + v1[jj].w;
    h1v.w = v1[jj].z + v1[jj].w + rf1;
    v0[jj] = h0v; v1[jj] = h1v;
  }

  #pragma unroll
  for (int k = 0; k < 4; ++k) {
    float4 b0, b1;
    b0.x = v0[k].x + v0[k + 1].x + v0[k + 2].x;
    b0.y = v0[k].y + v0[k + 1].y + v0[k + 2].y;
    b0.z = v0[k].z + v0[k + 1].z + v0[k + 2].z;
    b0.w = v0[k].w + v0[k + 1].w + v0[k + 2].w;
    b1.x = v1[k].x + v1[k + 1].x + v1[k + 2].x;
    b1.y = v1[k].y + v1[k + 1].y + v1[k + 2].y;
    b1.z = v1[k].z + v1[k + 1].z + v1[k + 2].z;
    b1.w = v1[k].w + v1[k + 1].w + v1[k + 2].w;
    const int rb = k * 32 + wq;
    sbox[(rb + 0) * 34 + dg] = f2bf2(b0.x, b1.x);
    sbox[(rb + 1) * 34 + dg] = f2bf2(b0.y, b1.y);
    sbox[(rb + 2) * 34 + dg] = f2bf2(b0.z, b1.z);
    sbox[(rb + 3) * 34 + dg] = f2bf2(b0.w, b1.w);
  }
  __syncthreads();

  // packed writeout (r8 layout): thread -> 32 bf16 of one hw row
  {
    const int r = t >> 1, half = t & 1;
    const u32* srcp = sbox + r * 34 + half * 16;
    uint2 a[8];
    #pragma unroll
    for (int q = 0; q < 8; ++q) a[q] = *(const uint2*)(srcp + q * 2);
    const int mt = n * 16 + ht * 2 + (r >> 6);
    const int mf = (r >> 4) & 3, r15 = r & 15;
    const int kt = dc * 2 + half;
    u16* dst = packA + ((size_t)(mt * 64 + kt) * 4 + mf) * 512 + r15 * 8;
    #pragma unroll
    for (int q = 0; q < 4; ++q) {        // q = hi
      uint4 b;
      b.x = a[2 * q].x; b.y = a[2 * q].y; b.z = a[2 * q + 1].x; b.w = a[2 * q + 1].y;
      *(uint4*)(dst + q * 128) = b;
    }
  }

  {
    float u0 = g0, u1 = g1;
    u0 += __shfl_xor(u0, 1, 8); u1 += __shfl_xor(u1, 1, 8);
    u0 += __shfl_xor(u0, 2, 8); u1 += __shfl_xor(u1, 2, 8);
    u0 += __shfl_xor(u0, 4, 8); u1 += __shfl_xor(u1, 4, 8);
    if (w4 == 0) {
      atomicAdd(&gbuf[n * D_ + d0 + dg * 2    ], u0);
      atomicAdd(&gbuf[n * D_ + d0 + dg * 2 + 1], u1);
    }
  }
}

// ---- K3: proj_w fp32 -> bf16, fragment-packed: packB[wq][kt][nf][lane][8] ----
__global__ __launch_bounds__(256) void k_wconv(const float* __restrict__ w, u16* __restrict__ packB) {
  const int i = blockIdx.x * 256 + threadIdx.x;   // 0..131071
  const int lane = i & 63, nf = (i >> 6) & 3, kt = (i >> 8) & 63, wq = i >> 14;  // wq 0..7
  const int r15 = lane & 15, hi = lane >> 4;
  const int f = wq * 64 + nf * 16 + r15;
  const int k = kt * 32 + hi * 8;
  const float* src = w + (size_t)f * D_ + k;
  float4 v0 = *(const float4*)(src);
  float4 v1 = *(const float4*)(src + 4);
  u32 r[4] = { f2bf2(v0.x, v0.y), f2bf2(v0.z, v0.w),
               f2bf2(v1.x, v1.y), f2bf2(v1.z, v1.w) };
  *(uint4*)(packB + (size_t)i * 8) = *(const uint4*)r;
}

// ---- K4: GEMM, M-split for TLP: 512 blocks x [32 hw x 512 f], 512 thr ----
// Full F per block -> l2norm epilogue stays in-block (no renorm pass).
// Same r8 pipeline: 4-buf A (2KB each) via global_load_lds, B->reg lead-1,
// vmcnt 5/4/0, one s_barrier/step. 2 blocks/CU for cross-block stall overlap.
__global__ __launch_bounds__(512) void k_gemm(const u16* __restrict__ packA,
    const u16* __restrict__ packB, const float* __restrict__ bias,
    float* __restrict__ outL) {
  const int mt32 = blockIdx.x;          // 0..511
  const int mt64 = mt32 >> 1;
  const int half = mt32 & 1;
  const int n  = mt32 >> 5;
  const int hw0 = (mt32 & 31) * 32;
  const int t = threadIdx.x;
  const int lane = t & 63, wv = t >> 6;
  const int r15 = lane & 15, hi = lane >> 4;

  __shared__ __align__(16) float smem_f[128 * 36];   // 18.4 KB; A bufs alias first 8 KB
  __shared__ float s_sq[8][32];
  __shared__ float s_rn[32];

  f32x4 acc[2][4];
  #pragma unroll
  for (int a = 0; a < 2; ++a)
    #pragma unroll
    for (int b = 0; b < 4; ++b) acc[a][b] = (f32x4){0.f, 0.f, 0.f, 0.f};

  // A: block owns mf {2*half, 2*half+1} of tile mt64; wave stages chunk (wv&1)
  const u16* asrc = packA + ((size_t)(mt64 * 64) * 4 + half * 2 + (wv & 1)) * 512 + lane * 8;
  const u16* bbase = packB + (size_t)wv * 131072 + lane * 8;

#define STAGE_A(KT) GLD_LDS16(asrc + (size_t)(KT) * 2048, \
    (char*)smem_f + ((KT) & 3) * 2048 + (wv & 1) * 1024)

  STAGE_A(0);
  STAGE_A(1);
  bf16x8 bc[4], bn[4];
  #pragma unroll
  for (int nf = 0; nf < 4; ++nf) bc[nf] = *(const bf16x8*)(bbase + nf * 512);

  for (int kt = 0; kt < 64; ++kt) {
    if (kt + 2 < 64) STAGE_A(kt + 2);
    if (kt + 1 < 64) {
      #pragma unroll
      for (int nf = 0; nf < 4; ++nf)
        bn[nf] = *(const bf16x8*)(bbase + ((kt + 1) * 4 + nf) * 512);
    }
    __builtin_amdgcn_sched_barrier(0);
    if (kt < 62) {
      asm volatile("s_waitcnt vmcnt(5)" ::: "memory");   // A(<=kt+1)+B(kt) retired
    } else if (kt == 62) {
      asm volatile("s_waitcnt vmcnt(4)" ::: "memory");
    } else {
      asm volatile("s_waitcnt vmcnt(0)" ::: "memory");
    }
    __builtin_amdgcn_sched_barrier(0);
    __builtin_amdgcn_s_barrier();                         // A tile kt visible
    __builtin_amdgcn_sched_barrier(0);

    const u16* sA = (const u16*)((const char*)smem_f + (kt & 3) * 2048);
    bf16x8 af[2];
    #pragma unroll
    for (int mf = 0; mf < 2; ++mf)
      af[mf] = *(const bf16x8*)(sA + mf * 512 + lane * 8);
    #pragma unroll
    for (int mf = 0; mf < 2; ++mf)
      #pragma unroll
      for (int nf = 0; nf < 4; ++nf)
        acc[mf][nf] = __builtin_amdgcn_mfma_f32_16x16x32_bf16(af[mf], bc[nf], acc[mf][nf], 0, 0, 0);
    #pragma unroll
    for (int nf = 0; nf < 4; ++nf) bc[nf] = bn[nf];
  }
#undef STAGE_A

  // epilogue: bias, per-row (hw) l2 norm over all 512 f, transposed store
  float badd[4];
  #pragma unroll
  for (int nf = 0; nf < 4; ++nf) badd[nf] = bias[wv * 64 + nf * 16 + r15];
  #pragma unroll
  for (int mf = 0; mf < 2; ++mf)
    #pragma unroll
    for (int nf = 0; nf < 4; ++nf)
      #pragma unroll
      for (int j = 0; j < 4; ++j) acc[mf][nf][j] += badd[nf];

  #pragma unroll
  for (int mf = 0; mf < 2; ++mf)
    #pragma unroll
    for (int j = 0; j < 4; ++j) {
      float s = 0.f;
      #pragma unroll
      for (int nf = 0; nf < 4; ++nf) { float v = acc[mf][nf][j]; s += v * v; }
      s += __shfl_xor(s, 1); s += __shfl_xor(s, 2); s += __shfl_xor(s, 4); s += __shfl_xor(s, 8);
      if ((lane & 15) == 0) s_sq[wv][mf * 16 + hi * 4 + j] = s;
    }
  __syncthreads();
  if (t < 32) {
    float s = 0.f;
    #pragma unroll
    for (int w8 = 0; w8 < 8; ++w8) s += s_sq[w8][t];
    s_rn[t] = 1.0f / fmaxf(sqrtf(s), 1e-12f);
  }
  __syncthreads();

  float* ct = smem_f;   // [128 f-rows][36] fp32
  for (int nf = 0; nf < 4; ++nf) {
    const int fi = wv * 16 + r15;
    #pragma unroll
    for (int mf = 0; mf < 2; ++mf)
      #pragma unroll
      for (int j = 0; j < 4; ++j) {
        int m = mf * 16 + hi * 4 + j;
        ct[fi * 36 + m] = acc[mf][nf][j] * s_rn[m];
      }
    __syncthreads();
    {
      int fr = t >> 2, mq = t & 3;
      int f = (fr >> 4) * 64 + nf * 16 + (fr & 15);
      float* dst = outL + ((size_t)(n * F_ + f)) * HW_ + hw0 + mq * 8;
      const float* srcp = ct + fr * 36 + mq * 8;
      float4 a0 = *(const float4*)(srcp);
      float4 a1 = *(const float4*)(srcp + 4);
      *(float4*)(dst) = a0; *(float4*)(dst + 4) = a1;
    }
    __syncthreads();
  }
}

// ---- K5: GeM finalize: gg = (gbuf/1024)^(1/p) ----
__global__ __launch_bounds__(256) void k_gem_fin(const float* __restrict__ gbuf,
    const float* __restrict__ pvec, float* __restrict__ gg) {
  int i = blockIdx.x * 256 + threadIdx.x;
  float p = pvec[0];
  float m = gbuf[i] * (1.0f / 1024.0f);
  gg[i] = (p == 3.0f) ? cbrtf(m) : powf(m, 1.0f / p);
}

// ---- K6: gproj[n][f] = dot(gg[n], W[f]) + b[f] ----
__global__ __launch_bounds__(256) void k_gproj(const float* __restrict__ w,
    const float* __restrict__ bias, const float* __restrict__ gg,
    float* __restrict__ gproj) {
  const int f = blockIdx.x;
  const int t = threadIdx.x;
  float wreg[8];
  #pragma unroll
  for (int j = 0; j < 8; ++j) wreg[j] = w[(size_t)f * D_ + t + j * 256];
  __shared__ float red[4];
  const int lane = t & 63, wv = t >> 6;
  for (int n = 0; n < N_; ++n) {
    float s = 0.f;
    #pragma unroll
    for (int j = 0; j < 8; ++j) s += wreg[j] * gg[n * D_ + t + j * 256];
    #pragma unroll
    for (int off = 32; off >= 1; off >>= 1) s += __shfl_down(s, off);
    if (lane == 0) red[wv] = s;
    __syncthreads();
    if (t == 0) gproj[n * F_ + f] = red[0] + red[1] + red[2] + red[3] + bias[f];
    __syncthreads();
  }
}

// ---- K7: l2norm g rows -> d_out[0:8192] ----
__global__ __launch_bounds__(512) void k_gnorm(const float* __restrict__ gproj, float* __restrict__ outg) {
  const int n = blockIdx.x;
  const int t = threadIdx.x;
  float v = gproj[n * F_ + t];
  float s = v * v;
  const int lane = t & 63, wv = t >> 6;
  #pragma unroll
  for (int off = 32; off >= 1; off >>= 1) s += __shfl_down(s, off);
  __shared__ float red[8];
  __shared__ float rtot;
  if (lane == 0) red[wv] = s;
  __syncthreads();
  if (t == 0) {
    float a = 0.f;
    #pragma unroll
    for (int i = 0; i < 8; ++i) a += red[i];
    rtot = 1.0f / fmaxf(sqrtf(a), 1e-12f);
  }
  __syncthreads();
  outg[n * F_ + t] = v * rtot;
}

extern "C" void kernel_launch(void* const* d_in, const int* in_sizes, int n_in,
                              void* d_out, int out_size, void* d_ws, size_t ws_size,
                              hipStream_t stream) {
  const float* x  = (const float*)d_in[0];
  const float* pw = (const float*)d_in[1];
  const float* pb = (const float*)d_in[2];
  const float* pv = (const float*)d_in[3];
  float* out = (float*)d_out;

  char* ws = (char*)d_ws;
  float* sumsq = (float*)ws;                                   // 64 KB
  float* gbuf  = (float*)(ws + 65536);                         // 128 KB
  float* gg    = (float*)(ws + 65536 + 131072);                // 128 KB
  float* gproj = (float*)(ws + 65536 + 2 * 131072);            // 32 KB
  u16*   packB = (u16*)(ws + 65536 + 2 * 131072 + 32768);      // 2 MiB
  u16*   packA = (u16*)(ws + 4u * 1024u * 1024u);              // 64 MiB

  k_zero<<<dim3(48), dim3(256), 0, stream>>>(sumsq);           // sumsq + gbuf
  k_sumsq<<<dim3(16, 32), dim3(256), 0, stream>>>(x, sumsq);
  k_wconv<<<dim3(512), dim3(256), 0, stream>>>(pw, packB);
  k_box2<<<dim3(16, 8, 32), dim3(256), 0, stream>>>(x, sumsq, pv, gbuf, packA);
  k_gem_fin<<<dim3(128), dim3(256), 0, stream>>>(gbuf, pv, gg);
  k_gproj<<<dim3(512), dim3(256), 0, stream>>>(pw, pb, gg, gproj);
  k_gnorm<<<dim3(16), dim3(512), 0, stream>>>(gproj, out);
  k_gemm<<<dim3(512), dim3(512), 0, stream>>>(packA, packB, pb, out + N_ * F_);
}